// Round 5
// baseline (586.715 us; speedup 1.0000x reference)
//
#include <hip/hip_runtime.h>

#define DIV_UP(a,b) (((a)+(b)-1)/(b))

#define CH   9216    // edges per partition block
#define CAP  7424    // max edges per 256-node bucket in sortfill (mean 4096)

// ---------------- CSR build: bucketed counting sort ----------------
// bucket = dst >> 8 (256 nodes per bucket)

__global__ __launch_bounds__(256) void k_hist1(const int* __restrict__ dst, int E,
                                               int NBK, int NB1,
                                               int* __restrict__ blk_hist) {
    __shared__ int hist[512];
    for (int i = threadIdx.x; i < NBK; i += 256) hist[i] = 0;
    __syncthreads();
    int base = blockIdx.x * CH;
    int lim = E - base; if (lim > CH) lim = CH;
    for (int i = threadIdx.x; i < lim; i += 256)
        atomicAdd(&hist[dst[base + i] >> 8], 1);
    __syncthreads();
    for (int b = threadIdx.x; b < NBK; b += 256)
        blk_hist[b * NB1 + blockIdx.x] = hist[b];   // bucket-major
}

__global__ __launch_bounds__(1024) void k_scan1(const int* __restrict__ blk_hist,
                                                int* __restrict__ blk_off,
                                                int* __restrict__ bkt_base,
                                                int NBK, int NB1, int E) {
    __shared__ int part[1024];
    int total = NBK * NB1;
    int chunk = DIV_UP(total, 1024);
    int t = threadIdx.x;
    int lo = t * chunk;
    int hi = lo + chunk; if (hi > total) hi = total;
    int s = 0;
    for (int i = lo; i < hi; i++) s += blk_hist[i];
    part[t] = s;
    __syncthreads();
    for (int o = 1; o < 1024; o <<= 1) {
        int v = (t >= o) ? part[t - o] : 0;
        __syncthreads();
        part[t] += v;
        __syncthreads();
    }
    int run = part[t] - s;   // exclusive prefix of this thread's chunk
    for (int i = lo; i < hi; i++) {
        blk_off[i] = run;
        if (i % NB1 == 0) bkt_base[i / NB1] = run;
        run += blk_hist[i];
    }
    if (t == 0) bkt_base[NBK] = E;
}

__global__ __launch_bounds__(256) void k_scatter1(const int* __restrict__ src,
                                                  const int* __restrict__ dst, int E,
                                                  int NBK, int NB1,
                                                  const int* __restrict__ blk_off,
                                                  unsigned int* __restrict__ part_arr) {
    __shared__ unsigned int   stage[CH];
    __shared__ unsigned short bko[CH];
    __shared__ int hist[512];
    __shared__ int cur[512];
    __shared__ int off[512];

    int t = threadIdx.x;
    hist[t] = 0; hist[t + 256] = 0;
    __syncthreads();

    int base = blockIdx.x * CH;
    int lim = E - base; if (lim > CH) lim = CH;

    for (int i = t; i < lim; i += 256)
        atomicAdd(&hist[dst[base + i] >> 8], 1);
    __syncthreads();

    int c0 = hist[t], c1 = hist[t + 256];
    for (int o = 1; o < 512; o <<= 1) {
        int v0 = (t >= o) ? hist[t - o] : 0;
        int v1 = hist[t + 256 - o];
        __syncthreads();
        hist[t] += v0;
        hist[t + 256] += v1;
        __syncthreads();
    }
    int e0 = hist[t] - c0;          // exclusive
    int e1 = hist[t + 256] - c1;
    cur[t] = e0; cur[t + 256] = e1;
    if (t < NBK)       off[t]       = blk_off[t * NB1 + blockIdx.x] - e0;
    if (t + 256 < NBK) off[t + 256] = blk_off[(t + 256) * NB1 + blockIdx.x] - e1;
    __syncthreads();

    for (int i = t; i < lim; i += 256) {
        int d = dst[base + i];
        int sv = src[base + i];
        int b = d >> 8;
        int slot = atomicAdd(&cur[b], 1);
        stage[slot] = ((unsigned int)sv << 8) | (unsigned int)(d & 255);
        bko[slot] = (unsigned short)b;
    }
    __syncthreads();

    for (int i = t; i < lim; i += 256) {
        int b = bko[i];
        part_arr[off[b] + i] = stage[i];
    }
}

__global__ __launch_bounds__(256) void k_sortfill(const unsigned int* __restrict__ part_arr,
                                                  const int* __restrict__ bkt_base,
                                                  int N, int E,
                                                  int* __restrict__ col,
                                                  int* __restrict__ rowptr,
                                                  float* __restrict__ inv_sqrt) {
    __shared__ unsigned int in_[CAP];
    __shared__ int outS[CAP];
    __shared__ int hist[256];
    __shared__ int scn[256];
    __shared__ int cur[256];

    int b = blockIdx.x;
    int base = bkt_base[b];
    int nb   = bkt_base[b + 1] - base;
    int t = threadIdx.x;

    hist[t] = 0;
    __syncthreads();

    for (int i = t; i < nb; i += 256) {
        unsigned int pk = part_arr[base + i];
        in_[i] = pk;
        atomicAdd(&hist[pk & 255u], 1);
    }
    __syncthreads();

    int cnt = hist[t];
    for (int o = 1; o < 256; o <<= 1) {
        int v = (t >= o) ? hist[t - o] : 0;
        __syncthreads();
        hist[t] += v;
        __syncthreads();
    }
    int excl = hist[t] - cnt;
    scn[t] = excl;
    cur[t] = 0;
    __syncthreads();

    for (int i = t; i < nb; i += 256) {
        unsigned int pk = in_[i];
        int d = (int)(pk & 255u);
        int r = atomicAdd(&cur[d], 1);
        outS[scn[d] + r] = (int)(pk >> 8);
    }
    __syncthreads();

    for (int i = t; i < nb; i += 256) col[base + i] = outS[i];

    int node = b * 256 + t;
    if (node < N) {
        rowptr[node] = base + excl;
        inv_sqrt[node] = rsqrtf((float)(cnt + 1));   // +1: self-loop
    }
    if (b == 0 && t == 0) rowptr[N] = E;
}

// ---------------- Register-tiled GEMM ----------------

__global__ __launch_bounds__(256, 3) void k_gemm_rt(const float* __restrict__ in,
                          const float* __restrict__ W,
                          const float* __restrict__ inv_sqrt,
                          float* __restrict__ out, int N) {
    __shared__ float xsT[32][132];
    __shared__ float ws[32][132];

    const int t = threadIdx.x;
    const int row0 = blockIdx.x * 128;
    const int lane = t & 63;
    const int wave = t >> 6;
    const int rg = ((wave >> 1) << 3) + (lane >> 3);  // 0..15 row group
    const int cg = ((wave & 1) << 3) + (lane & 7);    // 0..15 col group

    const float4* in4 = (const float4*)in;
    const float4* W4  = (const float4*)W;

    float4 acc[8][2];
    #pragma unroll
    for (int i = 0; i < 8; i++) {
        acc[i][0] = make_float4(0.f, 0.f, 0.f, 0.f);
        acc[i][1] = make_float4(0.f, 0.f, 0.f, 0.f);
    }

    const bool full = (row0 + 128 <= N);

    for (int kt = 0; kt < 4; kt++) {
        #pragma unroll
        for (int i = 0; i < 4; i++) {
            int idx = t + i * 256;
            int r  = idx >> 3;
            int c4 = idx & 7;
            int row = row0 + r;
            float4 v = make_float4(0.f, 0.f, 0.f, 0.f);
            if (full || row < N) v = in4[(size_t)row * 32 + kt * 8 + c4];
            xsT[c4 * 4 + 0][r] = v.x;
            xsT[c4 * 4 + 1][r] = v.y;
            xsT[c4 * 4 + 2][r] = v.z;
            xsT[c4 * 4 + 3][r] = v.w;
        }
        #pragma unroll
        for (int i = 0; i < 4; i++) {
            int idx = t + i * 256;
            int kk = idx >> 5;
            int c4 = idx & 31;
            *(float4*)&ws[kk][c4 * 4] = W4[(size_t)(kt * 32 + kk) * 32 + c4];
        }
        __syncthreads();

        #pragma unroll 8
        for (int k = 0; k < 32; k++) {
            float4 a0 = *(const float4*)&xsT[k][rg * 8];
            float4 a1 = *(const float4*)&xsT[k][rg * 8 + 4];
            float4 b0 = *(const float4*)&ws[k][cg * 8];
            float4 b1 = *(const float4*)&ws[k][cg * 8 + 4];
            float av[8] = {a0.x, a0.y, a0.z, a0.w, a1.x, a1.y, a1.z, a1.w};
            #pragma unroll
            for (int i = 0; i < 8; i++) {
                acc[i][0].x += av[i] * b0.x;
                acc[i][0].y += av[i] * b0.y;
                acc[i][0].z += av[i] * b0.z;
                acc[i][0].w += av[i] * b0.w;
                acc[i][1].x += av[i] * b1.x;
                acc[i][1].y += av[i] * b1.y;
                acc[i][1].z += av[i] * b1.z;
                acc[i][1].w += av[i] * b1.w;
            }
        }
        __syncthreads();
    }

    #pragma unroll
    for (int i = 0; i < 8; i++) {
        int row = row0 + rg * 8 + i;
        if (full || row < N) {
            float s = inv_sqrt[row];
            float4 o0 = acc[i][0], o1 = acc[i][1];
            o0.x *= s; o0.y *= s; o0.z *= s; o0.w *= s;
            o1.x *= s; o1.y *= s; o1.z *= s; o1.w *= s;
            float4* o = (float4*)(out + (size_t)row * 128);
            o[cg * 2]     = o0;
            o[cg * 2 + 1] = o1;
        }
    }
}

// ---------------- Aggregate v3 ----------------
// h[n] = relu(inv_sqrt[n]*(sum_{e in CSR[n]} g[col[e]] + g[n]) + b)
// 2 nodes per wave (32 lanes x float4 each). 8 gathers per node in flight,
// next iteration's col indices prefetched during gather latency. Uniform
// trip count across the wave (shfl-max of the two degrees); exhausted halves
// issue predicated dummy loads of the self row (L1-hot).

__global__ __launch_bounds__(256) void k_aggregate(const float* __restrict__ g,
                            const int* __restrict__ rowptr,
                            const int* __restrict__ col, const float* __restrict__ inv_sqrt,
                            const float* __restrict__ bias, float* __restrict__ out, int N) {
    int wgid = (blockIdx.x * 256 + threadIdx.x) >> 6;   // wave id
    int lane = threadIdx.x & 63;
    int h    = lane >> 5;                               // half: node select
    int hl   = lane & 31;                               // lane within half
    int wid  = wgid * 2 + h;
    bool valid = wid < N;
    int nid = valid ? wid : 0;

    int start = rowptr[nid];
    int end   = rowptr[nid + 1];
    int deg   = end - start;

    int odeg = __shfl_xor(deg, 32);
    int maxdeg = deg > odeg ? deg : odeg;

    const float4* g4 = (const float4*)g;
    float ax = 0.f, ay = 0.f, az = 0.f, aw = 0.f;

    int idx[8];
    #pragma unroll
    for (int i = 0; i < 8; i++)
        idx[i] = (i < deg) ? col[start + i] : nid;

    for (int tt = 0; tt < maxdeg; tt += 8) {
        float4 v[8];
        #pragma unroll
        for (int i = 0; i < 8; i++)
            v[i] = g4[(size_t)((unsigned)idx[i] * 32u + (unsigned)hl)];
        int nxt[8];
        #pragma unroll
        for (int i = 0; i < 8; i++) {
            int j = tt + 8 + i;
            nxt[i] = (j < deg) ? col[start + j] : nid;
        }
        #pragma unroll
        for (int i = 0; i < 8; i++) {
            if (tt + i < deg) {
                ax += v[i].x; ay += v[i].y; az += v[i].z; aw += v[i].w;
            }
        }
        #pragma unroll
        for (int i = 0; i < 8; i++) idx[i] = nxt[i];
    }

    // self loop
    float4 sv = g4[(unsigned)nid * 32u + (unsigned)hl];
    ax += sv.x; ay += sv.y; az += sv.z; aw += sv.w;

    float is = inv_sqrt[nid];
    float4 b = ((const float4*)bias)[hl];
    float4 res;
    res.x = fmaxf(is * ax + b.x, 0.f);
    res.y = fmaxf(is * ay + b.y, 0.f);
    res.z = fmaxf(is * az + b.z, 0.f);
    res.w = fmaxf(is * aw + b.w, 0.f);
    if (valid)
        ((float4*)(out + (size_t)wid * 128))[hl] = res;
}

// ---------------- Pool ----------------

__global__ void k_pool(const float* __restrict__ h, const int* __restrict__ batch,
                       float* __restrict__ pooled, int* __restrict__ counts, int N) {
    int f = threadIdx.x;            // 0..127
    int start = blockIdx.x * 256;
    int end = start + 256; if (end > N) end = N;
    if (start >= N) return;

    int cur = batch[start];
    float acc = 0.f;
    int cnt = 0;
    for (int r = start; r < end; r++) {
        int gi = batch[r];
        if (gi != cur) {
            atomicAdd(&pooled[(size_t)cur * 128 + f], acc);
            if (f == 0) atomicAdd(&counts[cur], cnt);
            acc = 0.f; cnt = 0; cur = gi;
        }
        acc += h[(size_t)r * 128 + f];
        cnt++;
    }
    atomicAdd(&pooled[(size_t)cur * 128 + f], acc);
    if (f == 0) atomicAdd(&counts[cur], cnt);
}

// ---------------- MLP head ----------------

__global__ void k_mlp(const float* __restrict__ pooled, const int* __restrict__ counts,
                      const float* __restrict__ Wc1, const float* __restrict__ bc1,
                      const float* __restrict__ Wc2, const float* __restrict__ bc2,
                      float* __restrict__ out, int G) {
    int g = blockIdx.x;
    int j = threadIdx.x;    // 0..63
    __shared__ float pm[128];
    __shared__ float z[64];

    float invc = 1.0f / fmaxf((float)counts[g], 1.0f);
    pm[j]      = pooled[(size_t)g * 128 + j] * invc;
    pm[j + 64] = pooled[(size_t)g * 128 + 64 + j] * invc;
    __syncthreads();

    float a = bc1[j];
    #pragma unroll 8
    for (int k = 0; k < 128; k++) a += pm[k] * Wc1[k * 64 + j];
    z[j] = fmaxf(a, 0.f);
    __syncthreads();

    if (j < 8) {
        float o = bc2[j];
        #pragma unroll 8
        for (int k = 0; k < 64; k++) o += z[k] * Wc2[k * 8 + j];
        out[(size_t)g * 8 + j] = o;
    }
}

// ---------------- launch ----------------

extern "C" void kernel_launch(void* const* d_in, const int* in_sizes, int n_in,
                              void* d_out, int out_size, void* d_ws, size_t ws_size,
                              hipStream_t stream) {
    const float* x    = (const float*)d_in[0];
    const int*   ei   = (const int*)d_in[1];
    const int*   batch= (const int*)d_in[2];
    const float* W1   = (const float*)d_in[4];
    const float* b1   = (const float*)d_in[5];
    const float* W2   = (const float*)d_in[6];
    const float* b2   = (const float*)d_in[7];
    const float* Wc1  = (const float*)d_in[8];
    const float* bc1  = (const float*)d_in[9];
    const float* Wc2  = (const float*)d_in[10];
    const float* bc2  = (const float*)d_in[11];
    float* out = (float*)d_out;

    const int N = in_sizes[0] / 128;
    const int E = in_sizes[1] / 2;
    const int G = out_size / 8;

    const int* src = ei;
    const int* dst = ei + E;

    const int NBK = DIV_UP(N, 256);     // buckets of 256 nodes
    const int NB1 = DIV_UP(E, CH);      // partition blocks

    char* p = (char*)d_ws;
    auto alloc = [&](size_t bytes) {
        char* q = p;
        p += (bytes + 255) & ~(size_t)255;
        return q;
    };
    float* bufA     = (float*)alloc((size_t)N * 128 * 4);
    float* bufB     = (float*)alloc((size_t)N * 128 * 4);
    int*   rowptr   = (int*)  alloc(((size_t)N + 1) * 4);
    int*   colA     = (int*)  alloc((size_t)E * 4);
    float* inv_sqrt = (float*)alloc((size_t)N * 4);
    int*   blk_hist = (int*)  alloc((size_t)NBK * NB1 * 4);
    int*   blk_off  = (int*)  alloc((size_t)NBK * NB1 * 4);
    int*   bkt_base = (int*)  alloc(((size_t)NBK + 1) * 4);
    float* pooled   = (float*)alloc((size_t)G * 128 * 4);
    int*   counts   = (int*)  alloc((size_t)G * 4);

    // part_arr aliases bufA: consumed by k_sortfill before the first GEMM writes bufA
    unsigned int* part_arr = (unsigned int*)bufA;

    hipMemsetAsync(pooled, 0, (size_t)G * 128 * 4, stream);
    hipMemsetAsync(counts, 0, (size_t)G * 4, stream);

    // CSR build (bucketed counting sort)
    k_hist1<<<NB1, 256, 0, stream>>>(dst, E, NBK, NB1, blk_hist);
    k_scan1<<<1, 1024, 0, stream>>>(blk_hist, blk_off, bkt_base, NBK, NB1, E);
    k_scatter1<<<NB1, 256, 0, stream>>>(src, dst, E, NBK, NB1, blk_off, part_arr);
    k_sortfill<<<NBK, 256, 0, stream>>>(part_arr, bkt_base, N, E, colA, rowptr, inv_sqrt);

    // layer 1
    k_gemm_rt<<<DIV_UP(N, 128), 256, 0, stream>>>(x, W1, inv_sqrt, bufA, N);
    k_aggregate<<<DIV_UP(N, 8), 256, 0, stream>>>(bufA, rowptr, colA, inv_sqrt, b1, bufB, N);

    // layer 2
    k_gemm_rt<<<DIV_UP(N, 128), 256, 0, stream>>>(bufB, W2, inv_sqrt, bufA, N);
    k_aggregate<<<DIV_UP(N, 8), 256, 0, stream>>>(bufA, rowptr, colA, inv_sqrt, b2, bufB, N);

    // pool + head
    k_pool<<<DIV_UP(N, 256), 128, 0, stream>>>(bufB, batch, pooled, counts, N);
    k_mlp<<<G, 64, 0, stream>>>(pooled, counts, Wc1, bc1, Wc2, bc2, out, G);
}